// Round 8
// baseline (474.395 us; speedup 1.0000x reference)
//
#include <hip/hip_runtime.h>

#define FI 256
#define FH 64
#define FO 128

// ---------------- common small kernels ----------------

__global__ void zero_i32(int* __restrict__ p, int n) {
    int i = blockIdx.x * 256 + threadIdx.x;
    if (i < n) p[i] = 0;
}

// degree count, 4 edges/thread for atomic MLP
__global__ void deg_cnt_kernel(const int* __restrict__ dst, int* __restrict__ cnt, int E) {
    int base = blockIdx.x * 1024 + threadIdx.x;
    #pragma unroll
    for (int q = 0; q < 4; ++q) {
        int e = base + q * 256;
        if (e < E) atomicAdd(&cnt[dst[e]], 1);
    }
}

__global__ void dinv_kernel(const int* __restrict__ cnt, float* __restrict__ dinv, int N) {
    int i = blockIdx.x * 256 + threadIdx.x;
    if (i < N) dinv[i] = rsqrtf((float)cnt[i] + 1.0f);
}

// ---------------- CSR build: scan + bucket scatter ----------------

__global__ void scan_block_kernel(const int* __restrict__ cnt, int* __restrict__ row_start,
                                  int* __restrict__ blksum, int N) {
    __shared__ int sh[256];
    int base = blockIdx.x * 1024 + threadIdx.x * 4;
    int v0 = 0, v1 = 0, v2 = 0, v3 = 0;
    if (base + 0 < N) v0 = cnt[base + 0];
    if (base + 1 < N) v1 = cnt[base + 1];
    if (base + 2 < N) v2 = cnt[base + 2];
    if (base + 3 < N) v3 = cnt[base + 3];
    sh[threadIdx.x] = v0 + v1 + v2 + v3;
    __syncthreads();
    for (int off = 1; off < 256; off <<= 1) {
        int t = (threadIdx.x >= off) ? sh[threadIdx.x - off] : 0;
        __syncthreads();
        sh[threadIdx.x] += t;
        __syncthreads();
    }
    int run = (threadIdx.x > 0) ? sh[threadIdx.x - 1] : 0;
    if (base + 0 < N) row_start[base + 0] = run; run += v0;
    if (base + 1 < N) row_start[base + 1] = run; run += v1;
    if (base + 2 < N) row_start[base + 2] = run; run += v2;
    if (base + 3 < N) row_start[base + 3] = run;
    if (threadIdx.x == 255) blksum[blockIdx.x] = sh[255];
}

__global__ void scan_top_kernel(int* __restrict__ blksum, int nb) {
    if (threadIdx.x == 0 && blockIdx.x == 0) {
        int acc = 0;
        for (int b = 0; b < nb; ++b) { int v = blksum[b]; blksum[b] = acc; acc += v; }
    }
}

__global__ void scan_add_kernel(int* __restrict__ row_start, int* __restrict__ pos,
                                const int* __restrict__ blksum, int N) {
    int i = blockIdx.x * 256 + threadIdx.x;
    if (i < N) {
        int v = row_start[i] + blksum[i >> 10];
        row_start[i] = v;
        pos[i] = v;
    }
}

// bucket-scatter: 4B record (src only — weights factored out), 4 edges/thread
__global__ void edge_sort_kernel(const int* __restrict__ src, const int* __restrict__ dst,
                                 int* __restrict__ pos, int* __restrict__ ssrc, int E) {
    int base = blockIdx.x * 1024 + threadIdx.x;
    #pragma unroll
    for (int q = 0; q < 4; ++q) {
        int e = base + q * 256;
        if (e < E) {
            int s = src[e], d = dst[e];
            int p = atomicAdd(&pos[d], 1);
            ssrc[p] = s;
        }
    }
}

// ---------------- gather-side aggregation (no atomics, no weights) ----------------
// hs = h * dinv convention: every stored feature row is pre-scaled by its node's dinv.

// layer 1: read hs1 from UPPER halves; write hs2 = relu(dinv*(agg + own) + b1)*dinv to LOWER
__global__ void gather_relu_kernel(const int* __restrict__ ssrc, const int* __restrict__ row_start,
                                   const int* __restrict__ cnt, const float* __restrict__ dinv,
                                   const float* __restrict__ b1, float* __restrict__ out, int N) {
    int node = blockIdx.x * 4 + (threadIdx.x >> 6);
    if (node >= N) return;
    int lane = threadIdx.x & 63;
    int beg = row_start[node];
    int n   = cnt[node];
    float acc = 0.f;
    int i = 0;
    for (; i + 7 < n; i += 8) {
        int s0 = ssrc[beg + i + 0], s1 = ssrc[beg + i + 1];
        int s2 = ssrc[beg + i + 2], s3 = ssrc[beg + i + 3];
        int s4 = ssrc[beg + i + 4], s5 = ssrc[beg + i + 5];
        int s6 = ssrc[beg + i + 6], s7 = ssrc[beg + i + 7];
        float h0 = out[(size_t)s0 * FO + FH + lane];
        float h1 = out[(size_t)s1 * FO + FH + lane];
        float h2 = out[(size_t)s2 * FO + FH + lane];
        float h3 = out[(size_t)s3 * FO + FH + lane];
        float h4 = out[(size_t)s4 * FO + FH + lane];
        float h5 = out[(size_t)s5 * FO + FH + lane];
        float h6 = out[(size_t)s6 * FO + FH + lane];
        float h7 = out[(size_t)s7 * FO + FH + lane];
        acc += ((h0 + h1) + (h2 + h3)) + ((h4 + h5) + (h6 + h7));
    }
    for (; i < n; ++i)
        acc += out[(size_t)ssrc[beg + i] * FO + FH + lane];
    float dv = dinv[node];
    float v = dv * (acc + out[(size_t)node * FO + FH + lane]) + b1[lane];
    out[(size_t)node * FO + lane] = fmaxf(v, 0.f) * dv;   // pre-scaled hs2
}

// layer 2: read hs2 from LOWER halves; write dinv*(agg + own) to UPPER
__global__ void gather_comb_kernel(const int* __restrict__ ssrc, const int* __restrict__ row_start,
                                   const int* __restrict__ cnt, const float* __restrict__ dinv,
                                   float* __restrict__ out, int N) {
    int node = blockIdx.x * 4 + (threadIdx.x >> 6);
    if (node >= N) return;
    int lane = threadIdx.x & 63;
    int beg = row_start[node];
    int n   = cnt[node];
    float acc = 0.f;
    int i = 0;
    for (; i + 7 < n; i += 8) {
        int s0 = ssrc[beg + i + 0], s1 = ssrc[beg + i + 1];
        int s2 = ssrc[beg + i + 2], s3 = ssrc[beg + i + 3];
        int s4 = ssrc[beg + i + 4], s5 = ssrc[beg + i + 5];
        int s6 = ssrc[beg + i + 6], s7 = ssrc[beg + i + 7];
        float h0 = out[(size_t)s0 * FO + lane];
        float h1 = out[(size_t)s1 * FO + lane];
        float h2 = out[(size_t)s2 * FO + lane];
        float h3 = out[(size_t)s3 * FO + lane];
        float h4 = out[(size_t)s4 * FO + lane];
        float h5 = out[(size_t)s5 * FO + lane];
        float h6 = out[(size_t)s6 * FO + lane];
        float h7 = out[(size_t)s7 * FO + lane];
        acc += ((h0 + h1) + (h2 + h3)) + ((h4 + h5) + (h6 + h7));
    }
    for (; i < n; ++i)
        acc += out[(size_t)ssrc[beg + i] * FO + lane];
    float dv = dinv[node];
    out[(size_t)node * FO + FH + lane] = dv * (acc + out[(size_t)node * FO + lane]);
}

// ---------------- fallback (atomic scatter) pieces — same hs convention ----------------

__global__ void zero_half_kernel(float* __restrict__ out, int half, int N) {
    int i = blockIdx.x * 256 + threadIdx.x;
    if (i >= N * FH) return;
    out[(size_t)(i >> 6) * FO + half + (i & 63)] = 0.f;
}

__global__ void scatter_half_kernel(const int* __restrict__ src, const int* __restrict__ dst,
                                    float* __restrict__ out, int rh, int wh, int E) {
    int e = blockIdx.x * 4 + (threadIdx.x >> 6);
    if (e >= E) return;
    int lane = threadIdx.x & 63;
    int s = src[e];
    int d = dst[e];
    atomicAdd(&out[(size_t)d * FO + wh + lane], out[(size_t)s * FO + rh + lane]);
}

// lower = relu(dinv*(lower_agg + upper_own) + b1) * dinv
__global__ void finish1_kernel(float* __restrict__ out, const float* __restrict__ dinv,
                               const float* __restrict__ b1, int N) {
    int i = blockIdx.x * 256 + threadIdx.x;
    if (i >= N * FH) return;
    int row = i >> 6;
    int c   = i & 63;
    size_t base = (size_t)row * FO;
    float dv = dinv[row];
    out[base + c] = fmaxf(dv * (out[base + c] + out[base + FH + c]) + b1[c], 0.f) * dv;
}

// upper = dinv*(upper_agg + lower_own)
__global__ void finish2_kernel(float* __restrict__ out, const float* __restrict__ dinv, int N) {
    int i = blockIdx.x * 256 + threadIdx.x;
    if (i >= N * FH) return;
    int row = i >> 6;
    int c   = i & 63;
    size_t base = (size_t)row * FO;
    float dv = dinv[row];
    out[base + FH + c] = dv * (out[base + FH + c] + out[base + c]);
}

// ---------------- dense kernels: register-tiled SGEMM ----------------

// mm1: hs1 = (x @ W1) * dinv[row] -> out[row][64..127]. Tile 128x64, 256 thr, 4x8/thread.
__global__ __launch_bounds__(256) void mm1_tiled(const float* __restrict__ x,
                                                 const float* __restrict__ W1,
                                                 const float* __restrict__ dinv,
                                                 float* __restrict__ out, int N) {
    __shared__ float xs[32][128];
    __shared__ float ws[32][64];
    int tid = threadIdx.x;
    int R0  = blockIdx.x * 128;
    int ty  = tid >> 3;
    int tx  = tid & 7;
    float acc[4][8];
    #pragma unroll
    for (int i = 0; i < 4; ++i)
        #pragma unroll
        for (int j = 0; j < 8; ++j) acc[i][j] = 0.f;

    int sr = tid >> 1;
    int sk = (tid & 1) * 16;
    bool row_ok = (R0 + sr) < N;
    const float* xrow = x + (size_t)(R0 + sr) * FI;

    for (int k0 = 0; k0 < FI; k0 += 32) {
        __syncthreads();
        #pragma unroll
        for (int q = 0; q < 4; ++q) {
            float4 v = row_ok ? *(const float4*)&xrow[k0 + sk + q * 4]
                              : make_float4(0.f, 0.f, 0.f, 0.f);
            xs[sk + q * 4 + 0][sr] = v.x;
            xs[sk + q * 4 + 1][sr] = v.y;
            xs[sk + q * 4 + 2][sr] = v.z;
            xs[sk + q * 4 + 3][sr] = v.w;
        }
        {
            int f = tid * 2;
            *(float4*)&ws[0][0 + f * 4]     = *(const float4*)&W1[(size_t)k0 * 64 + f * 4];
            *(float4*)&ws[0][0 + f * 4 + 4] = *(const float4*)&W1[(size_t)k0 * 64 + f * 4 + 4];
        }
        __syncthreads();
        #pragma unroll 4
        for (int k = 0; k < 32; ++k) {
            float4 a  = *(const float4*)&xs[k][ty * 4];
            float4 bl = *(const float4*)&ws[k][tx * 4];
            float4 bh = *(const float4*)&ws[k][32 + tx * 4];
            float av[4] = {a.x, a.y, a.z, a.w};
            float bv[8] = {bl.x, bl.y, bl.z, bl.w, bh.x, bh.y, bh.z, bh.w};
            #pragma unroll
            for (int i = 0; i < 4; ++i)
                #pragma unroll
                for (int j = 0; j < 8; ++j)
                    acc[i][j] = fmaf(av[i], bv[j], acc[i][j]);
        }
    }
    #pragma unroll
    for (int i = 0; i < 4; ++i) {
        int row = R0 + ty * 4 + i;
        if (row < N) {
            float dv = dinv[row];
            float* o = out + (size_t)row * FO + FH;
            *(float4*)&o[tx * 4]      = make_float4(acc[i][0] * dv, acc[i][1] * dv,
                                                    acc[i][2] * dv, acc[i][3] * dv);
            *(float4*)&o[32 + tx * 4] = make_float4(acc[i][4] * dv, acc[i][5] * dv,
                                                    acc[i][6] * dv, acc[i][7] * dv);
        }
    }
}

// mm2: out_row = upper_combined @ W2 + b2, in place (reads upper halves of own rows only).
__global__ __launch_bounds__(256) void mm2_tiled(const float* __restrict__ W2,
                                                 const float* __restrict__ b2,
                                                 float* __restrict__ out, int N) {
    __shared__ float xs[64][68];
    __shared__ float ws[64][128];
    int tid = threadIdx.x;
    int R0  = blockIdx.x * 64;
    int ty  = tid >> 4;
    int tx  = tid & 15;

    {
        int sr = tid >> 2;
        int l4 = tid & 3;
        int grow = R0 + sr;
        bool ok = grow < N;
        const float* orow = out + (size_t)grow * FO + FH;
        #pragma unroll
        for (int q = 0; q < 4; ++q) {
            int j0 = (l4 + 4 * q) * 4;
            float4 a = ok ? *(const float4*)&orow[j0] : make_float4(0.f, 0.f, 0.f, 0.f);
            xs[j0 + 0][sr] = a.x;
            xs[j0 + 1][sr] = a.y;
            xs[j0 + 2][sr] = a.z;
            xs[j0 + 3][sr] = a.w;
        }
    }
    #pragma unroll
    for (int q = 0; q < 8; ++q) {
        int f = tid + q * 256;
        *(float4*)&ws[f >> 5][(f & 31) * 4] = *(const float4*)&W2[(size_t)f * 4];
    }
    __syncthreads();

    float acc[4][8];
    #pragma unroll
    for (int i = 0; i < 4; ++i)
        #pragma unroll
        for (int j = 0; j < 8; ++j) acc[i][j] = 0.f;

    #pragma unroll 4
    for (int k = 0; k < FH; ++k) {
        float4 a  = *(const float4*)&xs[k][ty * 4];
        float4 bl = *(const float4*)&ws[k][tx * 4];
        float4 bh = *(const float4*)&ws[k][64 + tx * 4];
        float av[4] = {a.x, a.y, a.z, a.w};
        float bv[8] = {bl.x, bl.y, bl.z, bl.w, bh.x, bh.y, bh.z, bh.w};
        #pragma unroll
        for (int i = 0; i < 4; ++i)
            #pragma unroll
            for (int j = 0; j < 8; ++j)
                acc[i][j] = fmaf(av[i], bv[j], acc[i][j]);
    }

    float4 b2l = *(const float4*)&b2[tx * 4];
    float4 b2h = *(const float4*)&b2[64 + tx * 4];
    #pragma unroll
    for (int i = 0; i < 4; ++i) {
        int row = R0 + ty * 4 + i;
        if (row < N) {
            float* o = out + (size_t)row * FO;
            *(float4*)&o[tx * 4] = make_float4(acc[i][0] + b2l.x, acc[i][1] + b2l.y,
                                               acc[i][2] + b2l.z, acc[i][3] + b2l.w);
            *(float4*)&o[64 + tx * 4] = make_float4(acc[i][4] + b2h.x, acc[i][5] + b2h.y,
                                                    acc[i][6] + b2h.z, acc[i][7] + b2h.w);
        }
    }
}

extern "C" void kernel_launch(void* const* d_in, const int* in_sizes, int n_in,
                              void* d_out, int out_size, void* d_ws, size_t ws_size,
                              hipStream_t stream) {
    const float* x  = (const float*)d_in[0];
    const int*   ei = (const int*)d_in[1];
    const float* W1 = (const float*)d_in[2];
    const float* b1 = (const float*)d_in[3];
    const float* W2 = (const float*)d_in[4];
    const float* b2 = (const float*)d_in[5];
    float* out = (float*)d_out;

    int N = in_sizes[0] / FI;     // 50000
    int E = in_sizes[1] / 2;      // 1600000
    const int* src = ei;
    const int* dst = ei + E;

    char* w = (char*)d_ws;
    float* dinv      = (float*)w;            w += (size_t)N * 4;
    int*   cnt       = (int*)w;              w += (size_t)N * 4;
    int*   row_start = (int*)w;              w += (size_t)N * 4;
    int*   pos       = (int*)w;              w += (size_t)N * 4;
    int*   blksum    = (int*)w;              w += 256 * 4;
    int*   ssrc      = (int*)w;              w += (size_t)E * 4;
    size_t need = (size_t)(w - (char*)d_ws);   // ~7.2 MB

    int nb = (N + 1023) / 1024;

    zero_i32<<<(N + 255) / 256, 256, 0, stream>>>(cnt, N);
    deg_cnt_kernel<<<(E + 1023) / 1024, 256, 0, stream>>>(dst, cnt, E);
    dinv_kernel<<<(N + 255) / 256, 256, 0, stream>>>(cnt, dinv, N);

    if (ws_size >= need) {
        scan_block_kernel<<<nb, 256, 0, stream>>>(cnt, row_start, blksum, N);
        scan_top_kernel<<<1, 64, 0, stream>>>(blksum, nb);
        scan_add_kernel<<<(N + 255) / 256, 256, 0, stream>>>(row_start, pos, blksum, N);
        edge_sort_kernel<<<(E + 1023) / 1024, 256, 0, stream>>>(src, dst, pos, ssrc, E);

        mm1_tiled<<<(N + 127) / 128, 256, 0, stream>>>(x, W1, dinv, out, N);
        gather_relu_kernel<<<(N + 3) / 4, 256, 0, stream>>>(ssrc, row_start, cnt, dinv, b1, out, N);
        gather_comb_kernel<<<(N + 3) / 4, 256, 0, stream>>>(ssrc, row_start, cnt, dinv, out, N);
        mm2_tiled<<<(N + 63) / 64, 256, 0, stream>>>(W2, b2, out, N);
    } else {
        // fallback: atomic scatter path (same hs pre-scaling convention)
        mm1_tiled<<<(N + 127) / 128, 256, 0, stream>>>(x, W1, dinv, out, N);
        zero_half_kernel<<<((N * FH) + 255) / 256, 256, 0, stream>>>(out, 0, N);
        scatter_half_kernel<<<(E + 3) / 4, 256, 0, stream>>>(src, dst, out, FH, 0, E);
        finish1_kernel<<<((N * FH) + 255) / 256, 256, 0, stream>>>(out, dinv, b1, N);
        zero_half_kernel<<<((N * FH) + 255) / 256, 256, 0, stream>>>(out, FH, N);
        scatter_half_kernel<<<(E + 3) / 4, 256, 0, stream>>>(src, dst, out, 0, FH, E);
        finish2_kernel<<<((N * FH) + 255) / 256, 256, 0, stream>>>(out, dinv, N);
        mm2_tiled<<<(N + 63) / 64, 256, 0, stream>>>(W2, b2, out, N);
    }
}

// Round 9
// 463.030 us; speedup vs baseline: 1.0245x; 1.0245x over previous
//
#include <hip/hip_runtime.h>

#define FI 256
#define FH 64
#define FO 128
// ushort-view row stride = 256; bf16 h1 at ushort idx 128..191, bf16 hs2 at 192..255

__device__ __forceinline__ ushort f2bf(float x) {   // fp32 -> bf16 RNE
    unsigned b = __float_as_uint(x);
    b += 0x7fffu + ((b >> 16) & 1u);
    return (ushort)(b >> 16);
}
__device__ __forceinline__ float bf2f(ushort u) {
    return __uint_as_float(((unsigned)u) << 16);
}

// ---------------- common small kernels ----------------

__global__ void zero_i32(int* __restrict__ p, int n) {
    int i = blockIdx.x * 256 + threadIdx.x;
    if (i < n) p[i] = 0;
}

// degree count, 4 edges/thread (fire-and-forget atomics: no return dependency)
__global__ void deg_cnt_kernel(const int* __restrict__ dst, int* __restrict__ cnt, int E) {
    int base = blockIdx.x * 1024 + threadIdx.x;
    #pragma unroll
    for (int q = 0; q < 4; ++q) {
        int e = base + q * 256;
        if (e < E) atomicAdd(&cnt[dst[e]], 1);
    }
}

__global__ void dinv_kernel(const int* __restrict__ cnt, float* __restrict__ dinv, int N) {
    int i = blockIdx.x * 256 + threadIdx.x;
    if (i < N) dinv[i] = rsqrtf((float)cnt[i] + 1.0f);
}

// ---------------- CSR build: scan + bucket scatter ----------------

__global__ void scan_block_kernel(const int* __restrict__ cnt, int* __restrict__ row_start,
                                  int* __restrict__ blksum, int N) {
    __shared__ int sh[256];
    int base = blockIdx.x * 1024 + threadIdx.x * 4;
    int v0 = 0, v1 = 0, v2 = 0, v3 = 0;
    if (base + 0 < N) v0 = cnt[base + 0];
    if (base + 1 < N) v1 = cnt[base + 1];
    if (base + 2 < N) v2 = cnt[base + 2];
    if (base + 3 < N) v3 = cnt[base + 3];
    sh[threadIdx.x] = v0 + v1 + v2 + v3;
    __syncthreads();
    for (int off = 1; off < 256; off <<= 1) {
        int t = (threadIdx.x >= off) ? sh[threadIdx.x - off] : 0;
        __syncthreads();
        sh[threadIdx.x] += t;
        __syncthreads();
    }
    int run = (threadIdx.x > 0) ? sh[threadIdx.x - 1] : 0;
    if (base + 0 < N) row_start[base + 0] = run; run += v0;
    if (base + 1 < N) row_start[base + 1] = run; run += v1;
    if (base + 2 < N) row_start[base + 2] = run; run += v2;
    if (base + 3 < N) row_start[base + 3] = run;
    if (threadIdx.x == 255) blksum[blockIdx.x] = sh[255];
}

__global__ void scan_top_kernel(int* __restrict__ blksum, int nb) {
    if (threadIdx.x == 0 && blockIdx.x == 0) {
        int acc = 0;
        for (int b = 0; b < nb; ++b) { int v = blksum[b]; blksum[b] = acc; acc += v; }
    }
}

__global__ void scan_add_kernel(int* __restrict__ row_start, int* __restrict__ pos,
                                const int* __restrict__ blksum, int N) {
    int i = blockIdx.x * 256 + threadIdx.x;
    if (i < N) {
        int v = row_start[i] + blksum[i >> 10];
        row_start[i] = v;
        pos[i] = v;
    }
}

// bucket-scatter: 4B record (src only). 1 edge/thread — TLP beats fake ILP here (r8 lesson).
__global__ void edge_sort_kernel(const int* __restrict__ src, const int* __restrict__ dst,
                                 int* __restrict__ pos, int* __restrict__ ssrc, int E) {
    int e = blockIdx.x * 256 + threadIdx.x;
    if (e >= E) return;
    int s = src[e], d = dst[e];
    int p = atomicAdd(&pos[d], 1);
    ssrc[p] = s;
}

// ---------------- gather-side aggregation (no atomics, bf16 staged reads) ----------------
// hs convention: stored feature rows pre-scaled by dinv. h1(bf16) at ushort[128..191],
// hs2(bf16) at ushort[192..255], combined(fp32) at float[0..63]. Column-disjoint per phase.

// layer 1: gather bf16 h1; write bf16 hs2 = relu(dv*(agg+own) + b1)*dv
__global__ void gather_relu_kernel(const int* __restrict__ ssrc, const int* __restrict__ row_start,
                                   const int* __restrict__ cnt, const float* __restrict__ dinv,
                                   const float* __restrict__ b1, float* __restrict__ out, int N) {
    int node = blockIdx.x * 4 + (threadIdx.x >> 6);
    if (node >= N) return;
    int lane = threadIdx.x & 63;
    const ushort* hb = (const ushort*)out;
    int beg = row_start[node];
    int n   = cnt[node];
    float acc = 0.f;
    int i = 0;
    while (i < n && ((beg + i) & 3)) {              // peel to int4 alignment
        acc += bf2f(hb[(size_t)ssrc[beg + i] * 256 + 128 + lane]);
        ++i;
    }
    for (; i + 7 < n; i += 8) {
        int4 a = *(const int4*)&ssrc[beg + i];
        int4 b = *(const int4*)&ssrc[beg + i + 4];
        float h0 = bf2f(hb[(size_t)a.x * 256 + 128 + lane]);
        float h1 = bf2f(hb[(size_t)a.y * 256 + 128 + lane]);
        float h2 = bf2f(hb[(size_t)a.z * 256 + 128 + lane]);
        float h3 = bf2f(hb[(size_t)a.w * 256 + 128 + lane]);
        float h4 = bf2f(hb[(size_t)b.x * 256 + 128 + lane]);
        float h5 = bf2f(hb[(size_t)b.y * 256 + 128 + lane]);
        float h6 = bf2f(hb[(size_t)b.z * 256 + 128 + lane]);
        float h7 = bf2f(hb[(size_t)b.w * 256 + 128 + lane]);
        acc += ((h0 + h1) + (h2 + h3)) + ((h4 + h5) + (h6 + h7));
    }
    for (; i < n; ++i)
        acc += bf2f(hb[(size_t)ssrc[beg + i] * 256 + 128 + lane]);
    float dv = dinv[node];
    float own = bf2f(hb[(size_t)node * 256 + 128 + lane]);
    float v = dv * (acc + own) + b1[lane];
    ((ushort*)out)[(size_t)node * 256 + 192 + lane] = f2bf(fmaxf(v, 0.f) * dv);
}

// layer 2: gather bf16 hs2; write fp32 combined = dv*(agg+own) to float[0..63]
__global__ void gather_comb_kernel(const int* __restrict__ ssrc, const int* __restrict__ row_start,
                                   const int* __restrict__ cnt, const float* __restrict__ dinv,
                                   float* __restrict__ out, int N) {
    int node = blockIdx.x * 4 + (threadIdx.x >> 6);
    if (node >= N) return;
    int lane = threadIdx.x & 63;
    const ushort* hb = (const ushort*)out;
    int beg = row_start[node];
    int n   = cnt[node];
    float acc = 0.f;
    int i = 0;
    while (i < n && ((beg + i) & 3)) {
        acc += bf2f(hb[(size_t)ssrc[beg + i] * 256 + 192 + lane]);
        ++i;
    }
    for (; i + 7 < n; i += 8) {
        int4 a = *(const int4*)&ssrc[beg + i];
        int4 b = *(const int4*)&ssrc[beg + i + 4];
        float h0 = bf2f(hb[(size_t)a.x * 256 + 192 + lane]);
        float h1 = bf2f(hb[(size_t)a.y * 256 + 192 + lane]);
        float h2 = bf2f(hb[(size_t)a.z * 256 + 192 + lane]);
        float h3 = bf2f(hb[(size_t)a.w * 256 + 192 + lane]);
        float h4 = bf2f(hb[(size_t)b.x * 256 + 192 + lane]);
        float h5 = bf2f(hb[(size_t)b.y * 256 + 192 + lane]);
        float h6 = bf2f(hb[(size_t)b.z * 256 + 192 + lane]);
        float h7 = bf2f(hb[(size_t)b.w * 256 + 192 + lane]);
        acc += ((h0 + h1) + (h2 + h3)) + ((h4 + h5) + (h6 + h7));
    }
    for (; i < n; ++i)
        acc += bf2f(hb[(size_t)ssrc[beg + i] * 256 + 192 + lane]);
    float dv = dinv[node];
    float own = bf2f(hb[(size_t)node * 256 + 192 + lane]);
    out[(size_t)node * FO + lane] = dv * (acc + own);
}

// ---------------- dense kernels: register-tiled SGEMM ----------------

// mm1: hs1 = (x @ W1) * dinv[row] -> bf16 at ushort[128..191] of each row.
__global__ __launch_bounds__(256) void mm1_tiled(const float* __restrict__ x,
                                                 const float* __restrict__ W1,
                                                 const float* __restrict__ dinv,
                                                 float* __restrict__ out, int N) {
    __shared__ float xs[32][128];
    __shared__ float ws[32][64];
    int tid = threadIdx.x;
    int R0  = blockIdx.x * 128;
    int ty  = tid >> 3;
    int tx  = tid & 7;
    float acc[4][8];
    #pragma unroll
    for (int i = 0; i < 4; ++i)
        #pragma unroll
        for (int j = 0; j < 8; ++j) acc[i][j] = 0.f;

    int sr = tid >> 1;
    int sk = (tid & 1) * 16;
    bool row_ok = (R0 + sr) < N;
    const float* xrow = x + (size_t)(R0 + sr) * FI;

    for (int k0 = 0; k0 < FI; k0 += 32) {
        __syncthreads();
        #pragma unroll
        for (int q = 0; q < 4; ++q) {
            float4 v = row_ok ? *(const float4*)&xrow[k0 + sk + q * 4]
                              : make_float4(0.f, 0.f, 0.f, 0.f);
            xs[sk + q * 4 + 0][sr] = v.x;
            xs[sk + q * 4 + 1][sr] = v.y;
            xs[sk + q * 4 + 2][sr] = v.z;
            xs[sk + q * 4 + 3][sr] = v.w;
        }
        {
            int f = tid * 2;
            *(float4*)&ws[0][0 + f * 4]     = *(const float4*)&W1[(size_t)k0 * 64 + f * 4];
            *(float4*)&ws[0][0 + f * 4 + 4] = *(const float4*)&W1[(size_t)k0 * 64 + f * 4 + 4];
        }
        __syncthreads();
        #pragma unroll 4
        for (int k = 0; k < 32; ++k) {
            float4 a  = *(const float4*)&xs[k][ty * 4];
            float4 bl = *(const float4*)&ws[k][tx * 4];
            float4 bh = *(const float4*)&ws[k][32 + tx * 4];
            float av[4] = {a.x, a.y, a.z, a.w};
            float bv[8] = {bl.x, bl.y, bl.z, bl.w, bh.x, bh.y, bh.z, bh.w};
            #pragma unroll
            for (int i = 0; i < 4; ++i)
                #pragma unroll
                for (int j = 0; j < 8; ++j)
                    acc[i][j] = fmaf(av[i], bv[j], acc[i][j]);
        }
    }
    #pragma unroll
    for (int i = 0; i < 4; ++i) {
        int row = R0 + ty * 4 + i;
        if (row < N) {
            float dv = dinv[row];
            ushort* ob = (ushort*)out + (size_t)row * 256 + 128;
            ushort4 lo = {f2bf(acc[i][0] * dv), f2bf(acc[i][1] * dv),
                          f2bf(acc[i][2] * dv), f2bf(acc[i][3] * dv)};
            ushort4 hi = {f2bf(acc[i][4] * dv), f2bf(acc[i][5] * dv),
                          f2bf(acc[i][6] * dv), f2bf(acc[i][7] * dv)};
            *(ushort4*)&ob[tx * 4]      = lo;
            *(ushort4*)&ob[32 + tx * 4] = hi;
        }
    }
}

// mm2: out_row = combined(float[0..63]) @ W2 + b2, in place.
__global__ __launch_bounds__(256) void mm2_tiled(const float* __restrict__ W2,
                                                 const float* __restrict__ b2,
                                                 float* __restrict__ out, int N) {
    __shared__ float xs[64][68];
    __shared__ float ws[64][128];
    int tid = threadIdx.x;
    int R0  = blockIdx.x * 64;
    int ty  = tid >> 4;
    int tx  = tid & 15;

    {
        int sr = tid >> 2;
        int l4 = tid & 3;
        int grow = R0 + sr;
        bool ok = grow < N;
        const float* orow = out + (size_t)grow * FO;    // combined in lower half
        #pragma unroll
        for (int q = 0; q < 4; ++q) {
            int j0 = (l4 + 4 * q) * 4;
            float4 a = ok ? *(const float4*)&orow[j0] : make_float4(0.f, 0.f, 0.f, 0.f);
            xs[j0 + 0][sr] = a.x;
            xs[j0 + 1][sr] = a.y;
            xs[j0 + 2][sr] = a.z;
            xs[j0 + 3][sr] = a.w;
        }
    }
    #pragma unroll
    for (int q = 0; q < 8; ++q) {
        int f = tid + q * 256;
        *(float4*)&ws[f >> 5][(f & 31) * 4] = *(const float4*)&W2[(size_t)f * 4];
    }
    __syncthreads();

    float acc[4][8];
    #pragma unroll
    for (int i = 0; i < 4; ++i)
        #pragma unroll
        for (int j = 0; j < 8; ++j) acc[i][j] = 0.f;

    #pragma unroll 4
    for (int k = 0; k < FH; ++k) {
        float4 a  = *(const float4*)&xs[k][ty * 4];
        float4 bl = *(const float4*)&ws[k][tx * 4];
        float4 bh = *(const float4*)&ws[k][64 + tx * 4];
        float av[4] = {a.x, a.y, a.z, a.w};
        float bv[8] = {bl.x, bl.y, bl.z, bl.w, bh.x, bh.y, bh.z, bh.w};
        #pragma unroll
        for (int i = 0; i < 4; ++i)
            #pragma unroll
            for (int j = 0; j < 8; ++j)
                acc[i][j] = fmaf(av[i], bv[j], acc[i][j]);
    }

    float4 b2l = *(const float4*)&b2[tx * 4];
    float4 b2h = *(const float4*)&b2[64 + tx * 4];
    #pragma unroll
    for (int i = 0; i < 4; ++i) {
        int row = R0 + ty * 4 + i;
        if (row < N) {
            float* o = out + (size_t)row * FO;
            *(float4*)&o[tx * 4] = make_float4(acc[i][0] + b2l.x, acc[i][1] + b2l.y,
                                               acc[i][2] + b2l.z, acc[i][3] + b2l.w);
            *(float4*)&o[64 + tx * 4] = make_float4(acc[i][4] + b2h.x, acc[i][5] + b2h.y,
                                                    acc[i][6] + b2h.z, acc[i][7] + b2h.w);
        }
    }
}

// ---------------- fallback (atomic scatter) pieces — bf16-compatible ----------------

// expand bf16 hs1 (ushort[128..191]) -> fp32 upper half floats[64..127]; one wave per row
__global__ void expand_hs1_kernel(float* __restrict__ out, int N) {
    int row = blockIdx.x * 4 + (threadIdx.x >> 6);
    if (row >= N) return;
    int lane = threadIdx.x & 63;
    float v = bf2f(((const ushort*)out)[(size_t)row * 256 + 128 + lane]);  // wave-lockstep safe
    out[(size_t)row * FO + FH + lane] = v;
}

__global__ void zero_half_kernel(float* __restrict__ out, int half, int N) {
    int i = blockIdx.x * 256 + threadIdx.x;
    if (i >= N * FH) return;
    out[(size_t)(i >> 6) * FO + half + (i & 63)] = 0.f;
}

__global__ void scatter_half_kernel(const int* __restrict__ src, const int* __restrict__ dst,
                                    float* __restrict__ out, int rh, int wh, int E) {
    int e = blockIdx.x * 4 + (threadIdx.x >> 6);
    if (e >= E) return;
    int lane = threadIdx.x & 63;
    int s = src[e];
    int d = dst[e];
    atomicAdd(&out[(size_t)d * FO + wh + lane], out[(size_t)s * FO + rh + lane]);
}

// lower = relu(dv*(lower_agg + upper_own_hs1) + b1) * dv   (fp32 hs2)
__global__ void finish1_kernel(float* __restrict__ out, const float* __restrict__ dinv,
                               const float* __restrict__ b1, int N) {
    int i = blockIdx.x * 256 + threadIdx.x;
    if (i >= N * FH) return;
    int row = i >> 6;
    int c   = i & 63;
    size_t base = (size_t)row * FO;
    float dv = dinv[row];
    out[base + c] = fmaxf(dv * (out[base + c] + out[base + FH + c]) + b1[c], 0.f) * dv;
}

// lower = dv*(upper_agg + lower_own_hs2)   (combined for mm2)
__global__ void finish2_kernel(float* __restrict__ out, const float* __restrict__ dinv, int N) {
    int i = blockIdx.x * 256 + threadIdx.x;
    if (i >= N * FH) return;
    int row = i >> 6;
    int c   = i & 63;
    size_t base = (size_t)row * FO;
    float dv = dinv[row];
    out[base + c] = dv * (out[base + FH + c] + out[base + c]);
}

extern "C" void kernel_launch(void* const* d_in, const int* in_sizes, int n_in,
                              void* d_out, int out_size, void* d_ws, size_t ws_size,
                              hipStream_t stream) {
    const float* x  = (const float*)d_in[0];
    const int*   ei = (const int*)d_in[1];
    const float* W1 = (const float*)d_in[2];
    const float* b1 = (const float*)d_in[3];
    const float* W2 = (const float*)d_in[4];
    const float* b2 = (const float*)d_in[5];
    float* out = (float*)d_out;

    int N = in_sizes[0] / FI;     // 50000
    int E = in_sizes[1] / 2;      // 1600000
    const int* src = ei;
    const int* dst = ei + E;

    char* w = (char*)d_ws;
    float* dinv      = (float*)w;            w += (size_t)N * 4;
    int*   cnt       = (int*)w;              w += (size_t)N * 4;
    int*   row_start = (int*)w;              w += (size_t)N * 4;
    int*   pos       = (int*)w;              w += (size_t)N * 4;
    int*   blksum    = (int*)w;              w += 256 * 4;
    int*   ssrc      = (int*)w;              w += (size_t)E * 4;
    size_t need = (size_t)(w - (char*)d_ws);   // ~7.2 MB

    int nb = (N + 1023) / 1024;

    zero_i32<<<(N + 255) / 256, 256, 0, stream>>>(cnt, N);
    deg_cnt_kernel<<<(E + 1023) / 1024, 256, 0, stream>>>(dst, cnt, E);
    dinv_kernel<<<(N + 255) / 256, 256, 0, stream>>>(cnt, dinv, N);

    if (ws_size >= need) {
        scan_block_kernel<<<nb, 256, 0, stream>>>(cnt, row_start, blksum, N);
        scan_top_kernel<<<1, 64, 0, stream>>>(blksum, nb);
        scan_add_kernel<<<(N + 255) / 256, 256, 0, stream>>>(row_start, pos, blksum, N);
        edge_sort_kernel<<<(E + 255) / 256, 256, 0, stream>>>(src, dst, pos, ssrc, E);

        mm1_tiled<<<(N + 127) / 128, 256, 0, stream>>>(x, W1, dinv, out, N);
        gather_relu_kernel<<<(N + 3) / 4, 256, 0, stream>>>(ssrc, row_start, cnt, dinv, b1, out, N);
        gather_comb_kernel<<<(N + 3) / 4, 256, 0, stream>>>(ssrc, row_start, cnt, dinv, out, N);
        mm2_tiled<<<(N + 63) / 64, 256, 0, stream>>>(W2, b2, out, N);
    } else {
        // fallback: atomic scatter path
        mm1_tiled<<<(N + 127) / 128, 256, 0, stream>>>(x, W1, dinv, out, N);
        expand_hs1_kernel<<<(N + 3) / 4, 256, 0, stream>>>(out, N);
        zero_half_kernel<<<((N * FH) + 255) / 256, 256, 0, stream>>>(out, 0, N);
        scatter_half_kernel<<<(E + 3) / 4, 256, 0, stream>>>(src, dst, out, FH, 0, E);
        finish1_kernel<<<((N * FH) + 255) / 256, 256, 0, stream>>>(out, dinv, b1, N);
        zero_half_kernel<<<((N * FH) + 255) / 256, 256, 0, stream>>>(out, FH, N);
        scatter_half_kernel<<<(E + 3) / 4, 256, 0, stream>>>(src, dst, out, 0, FH, E);
        finish2_kernel<<<((N * FH) + 255) / 256, 256, 0, stream>>>(out, dinv, N);
        mm2_tiled<<<(N + 63) / 64, 256, 0, stream>>>(W2, b2, out, N);
    }
}

// Round 10
// 391.151 us; speedup vs baseline: 1.2128x; 1.1838x over previous
//
#include <hip/hip_runtime.h>

#define FI 256
#define FH 64
#define FO 128
// ushort-view row stride 256: bf16 h1 at ushort[128..191], bf16 hrelu at [192..255],
// fp32 combined at float[0..63].

__device__ __forceinline__ ushort f2bf(float x) {   // fp32 -> bf16 RNE
    unsigned b = __float_as_uint(x);
    b += 0x7fffu + ((b >> 16) & 1u);
    return (ushort)(b >> 16);
}
__device__ __forceinline__ float bf2f(ushort u) {
    return __uint_as_float(((unsigned)u) << 16);
}

// ---------------- common small kernels ----------------

__global__ void zero_i32(int* __restrict__ p, int n) {
    int i = blockIdx.x * 256 + threadIdx.x;
    if (i < n) p[i] = 0;
}

__global__ void deg_cnt_kernel(const int* __restrict__ dst, int* __restrict__ cnt, int E) {
    int base = blockIdx.x * 1024 + threadIdx.x;
    #pragma unroll
    for (int q = 0; q < 4; ++q) {
        int e = base + q * 256;
        if (e < E) atomicAdd(&cnt[dst[e]], 1);
    }
}

__global__ void dinv_kernel(const int* __restrict__ cnt, float* __restrict__ dinv, int N) {
    int i = blockIdx.x * 256 + threadIdx.x;
    if (i < N) dinv[i] = rsqrtf((float)cnt[i] + 1.0f);
}

// ---------------- CSR build: scan + bucket scatter ----------------

__global__ void scan_block_kernel(const int* __restrict__ cnt, int* __restrict__ row_start,
                                  int* __restrict__ blksum, int N) {
    __shared__ int sh[256];
    int base = blockIdx.x * 1024 + threadIdx.x * 4;
    int v0 = 0, v1 = 0, v2 = 0, v3 = 0;
    if (base + 0 < N) v0 = cnt[base + 0];
    if (base + 1 < N) v1 = cnt[base + 1];
    if (base + 2 < N) v2 = cnt[base + 2];
    if (base + 3 < N) v3 = cnt[base + 3];
    sh[threadIdx.x] = v0 + v1 + v2 + v3;
    __syncthreads();
    for (int off = 1; off < 256; off <<= 1) {
        int t = (threadIdx.x >= off) ? sh[threadIdx.x - off] : 0;
        __syncthreads();
        sh[threadIdx.x] += t;
        __syncthreads();
    }
    int run = (threadIdx.x > 0) ? sh[threadIdx.x - 1] : 0;
    if (base + 0 < N) row_start[base + 0] = run; run += v0;
    if (base + 1 < N) row_start[base + 1] = run; run += v1;
    if (base + 2 < N) row_start[base + 2] = run; run += v2;
    if (base + 3 < N) row_start[base + 3] = run;
    if (threadIdx.x == 255) blksum[blockIdx.x] = sh[255];
}

__global__ void scan_top_kernel(int* __restrict__ blksum, int nb) {
    if (threadIdx.x == 0 && blockIdx.x == 0) {
        int acc = 0;
        for (int b = 0; b < nb; ++b) { int v = blksum[b]; blksum[b] = acc; acc += v; }
    }
}

__global__ void scan_add_kernel(int* __restrict__ row_start, int* __restrict__ pos,
                                const int* __restrict__ blksum, int N) {
    int i = blockIdx.x * 256 + threadIdx.x;
    if (i < N) {
        int v = row_start[i] + blksum[i >> 10];
        row_start[i] = v;
        pos[i] = v;
    }
}

// bucket-scatter: r7-exact configuration (measured 80us): 1 edge/thread,
// weighted 8B int2 record (src, dinv[s]*dinv[d]).
__global__ void edge_sort_kernel(const int* __restrict__ src, const int* __restrict__ dst,
                                 const float* __restrict__ dinv, int* __restrict__ pos,
                                 int2* __restrict__ rec, int E) {
    int e = blockIdx.x * 256 + threadIdx.x;
    if (e >= E) return;
    int s = src[e], d = dst[e];
    int p = atomicAdd(&pos[d], 1);
    int2 r;
    r.x = s;
    r.y = __float_as_int(dinv[s] * dinv[d]);
    rec[p] = r;
}

// ---------------- gather-side aggregation: 4 edges per wave-instruction ----------------
// Wave = 1 node. Lane L: g = L>>4 (edge slot), q = L&15 (feature quad, 4 bf16 = 8B).
// 16 edges per outer iteration -> 4 outstanding 8B gathers per lane.

// layer 1: gather bf16 h1 (cols [128..191]); write bf16 hrelu = relu(acc + dv^2*own + b1)
__global__ void gather_relu_kernel(const int2* __restrict__ rec, const int* __restrict__ row_start,
                                   const int* __restrict__ cnt, const float* __restrict__ dinv,
                                   const float* __restrict__ b1, float* __restrict__ out, int N) {
    int node = blockIdx.x * 4 + (threadIdx.x >> 6);
    if (node >= N) return;
    int L = threadIdx.x & 63;
    int g = L >> 4;
    int q = L & 15;
    const ushort* hb = (const ushort*)out;
    int beg = row_start[node];
    int n   = cnt[node];
    float4 acc = make_float4(0.f, 0.f, 0.f, 0.f);
    for (int i = 0; i < n; i += 16) {
        #pragma unroll
        for (int u = 0; u < 4; ++u) {
            int idx = i + u * 4 + g;
            int2 r = (idx < n) ? rec[beg + idx] : make_int2(node, 0);
            float w = __int_as_float(r.y);
            uint2 hv = *(const uint2*)(hb + (size_t)r.x * 256 + 128 + q * 4);
            acc.x = fmaf(bf2f((ushort)(hv.x & 0xffffu)), w, acc.x);
            acc.y = fmaf(bf2f((ushort)(hv.x >> 16)),     w, acc.y);
            acc.z = fmaf(bf2f((ushort)(hv.y & 0xffffu)), w, acc.z);
            acc.w = fmaf(bf2f((ushort)(hv.y >> 16)),     w, acc.w);
        }
    }
    acc.x += __shfl_xor(acc.x, 16, 64);
    acc.y += __shfl_xor(acc.y, 16, 64);
    acc.z += __shfl_xor(acc.z, 16, 64);
    acc.w += __shfl_xor(acc.w, 16, 64);
    acc.x += __shfl_xor(acc.x, 32, 64);
    acc.y += __shfl_xor(acc.y, 32, 64);
    acc.z += __shfl_xor(acc.z, 32, 64);
    acc.w += __shfl_xor(acc.w, 32, 64);
    if (L < 16) {
        float dv = dinv[node];
        float dv2 = dv * dv;
        uint2 ho = *(const uint2*)(hb + (size_t)node * 256 + 128 + q * 4);
        float4 b = *(const float4*)&b1[q * 4];
        float r0 = fmaxf(acc.x + dv2 * bf2f((ushort)(ho.x & 0xffffu)) + b.x, 0.f);
        float r1 = fmaxf(acc.y + dv2 * bf2f((ushort)(ho.x >> 16))     + b.y, 0.f);
        float r2 = fmaxf(acc.z + dv2 * bf2f((ushort)(ho.y & 0xffffu)) + b.z, 0.f);
        float r3 = fmaxf(acc.w + dv2 * bf2f((ushort)(ho.y >> 16))     + b.w, 0.f);
        ushort4 st = {f2bf(r0), f2bf(r1), f2bf(r2), f2bf(r3)};
        *(ushort4*)((ushort*)out + (size_t)node * 256 + 192 + q * 4) = st;
    }
}

// layer 2: gather bf16 hrelu (cols [192..255]); write fp32 combined to float[0..63]
__global__ void gather_comb_kernel(const int2* __restrict__ rec, const int* __restrict__ row_start,
                                   const int* __restrict__ cnt, const float* __restrict__ dinv,
                                   float* __restrict__ out, int N) {
    int node = blockIdx.x * 4 + (threadIdx.x >> 6);
    if (node >= N) return;
    int L = threadIdx.x & 63;
    int g = L >> 4;
    int q = L & 15;
    const ushort* hb = (const ushort*)out;
    int beg = row_start[node];
    int n   = cnt[node];
    float4 acc = make_float4(0.f, 0.f, 0.f, 0.f);
    for (int i = 0; i < n; i += 16) {
        #pragma unroll
        for (int u = 0; u < 4; ++u) {
            int idx = i + u * 4 + g;
            int2 r = (idx < n) ? rec[beg + idx] : make_int2(node, 0);
            float w = __int_as_float(r.y);
            uint2 hv = *(const uint2*)(hb + (size_t)r.x * 256 + 192 + q * 4);
            acc.x = fmaf(bf2f((ushort)(hv.x & 0xffffu)), w, acc.x);
            acc.y = fmaf(bf2f((ushort)(hv.x >> 16)),     w, acc.y);
            acc.z = fmaf(bf2f((ushort)(hv.y & 0xffffu)), w, acc.z);
            acc.w = fmaf(bf2f((ushort)(hv.y >> 16)),     w, acc.w);
        }
    }
    acc.x += __shfl_xor(acc.x, 16, 64);
    acc.y += __shfl_xor(acc.y, 16, 64);
    acc.z += __shfl_xor(acc.z, 16, 64);
    acc.w += __shfl_xor(acc.w, 16, 64);
    acc.x += __shfl_xor(acc.x, 32, 64);
    acc.y += __shfl_xor(acc.y, 32, 64);
    acc.z += __shfl_xor(acc.z, 32, 64);
    acc.w += __shfl_xor(acc.w, 32, 64);
    if (L < 16) {
        float dv = dinv[node];
        float dv2 = dv * dv;
        uint2 ho = *(const uint2*)(hb + (size_t)node * 256 + 192 + q * 4);
        float4 o;
        o.x = acc.x + dv2 * bf2f((ushort)(ho.x & 0xffffu));
        o.y = acc.y + dv2 * bf2f((ushort)(ho.x >> 16));
        o.z = acc.z + dv2 * bf2f((ushort)(ho.y & 0xffffu));
        o.w = acc.w + dv2 * bf2f((ushort)(ho.y >> 16));
        *(float4*)&out[(size_t)node * FO + q * 4] = o;
    }
}

// ---------------- dense kernels: register-tiled SGEMM ----------------

// mm1: h1 = x @ W1 -> bf16 at ushort[128..191] of each row (plain, unscaled).
__global__ __launch_bounds__(256) void mm1_tiled(const float* __restrict__ x,
                                                 const float* __restrict__ W1,
                                                 float* __restrict__ out, int N) {
    __shared__ float xs[32][128];
    __shared__ float ws[32][64];
    int tid = threadIdx.x;
    int R0  = blockIdx.x * 128;
    int ty  = tid >> 3;
    int tx  = tid & 7;
    float acc[4][8];
    #pragma unroll
    for (int i = 0; i < 4; ++i)
        #pragma unroll
        for (int j = 0; j < 8; ++j) acc[i][j] = 0.f;

    int sr = tid >> 1;
    int sk = (tid & 1) * 16;
    bool row_ok = (R0 + sr) < N;
    const float* xrow = x + (size_t)(R0 + sr) * FI;

    for (int k0 = 0; k0 < FI; k0 += 32) {
        __syncthreads();
        #pragma unroll
        for (int q = 0; q < 4; ++q) {
            float4 v = row_ok ? *(const float4*)&xrow[k0 + sk + q * 4]
                              : make_float4(0.f, 0.f, 0.f, 0.f);
            xs[sk + q * 4 + 0][sr] = v.x;
            xs[sk + q * 4 + 1][sr] = v.y;
            xs[sk + q * 4 + 2][sr] = v.z;
            xs[sk + q * 4 + 3][sr] = v.w;
        }
        {
            int f = tid * 2;
            *(float4*)&ws[0][0 + f * 4]     = *(const float4*)&W1[(size_t)k0 * 64 + f * 4];
            *(float4*)&ws[0][0 + f * 4 + 4] = *(const float4*)&W1[(size_t)k0 * 64 + f * 4 + 4];
        }
        __syncthreads();
        #pragma unroll 4
        for (int k = 0; k < 32; ++k) {
            float4 a  = *(const float4*)&xs[k][ty * 4];
            float4 bl = *(const float4*)&ws[k][tx * 4];
            float4 bh = *(const float4*)&ws[k][32 + tx * 4];
            float av[4] = {a.x, a.y, a.z, a.w};
            float bv[8] = {bl.x, bl.y, bl.z, bl.w, bh.x, bh.y, bh.z, bh.w};
            #pragma unroll
            for (int i = 0; i < 4; ++i)
                #pragma unroll
                for (int j = 0; j < 8; ++j)
                    acc[i][j] = fmaf(av[i], bv[j], acc[i][j]);
        }
    }
    #pragma unroll
    for (int i = 0; i < 4; ++i) {
        int row = R0 + ty * 4 + i;
        if (row < N) {
            ushort* ob = (ushort*)out + (size_t)row * 256 + 128;
            ushort4 lo = {f2bf(acc[i][0]), f2bf(acc[i][1]), f2bf(acc[i][2]), f2bf(acc[i][3])};
            ushort4 hi = {f2bf(acc[i][4]), f2bf(acc[i][5]), f2bf(acc[i][6]), f2bf(acc[i][7])};
            *(ushort4*)&ob[tx * 4]      = lo;
            *(ushort4*)&ob[32 + tx * 4] = hi;
        }
    }
}

// mm2: out_row = combined(float[0..63]) @ W2 + b2, in place.
__global__ __launch_bounds__(256) void mm2_tiled(const float* __restrict__ W2,
                                                 const float* __restrict__ b2,
                                                 float* __restrict__ out, int N) {
    __shared__ float xs[64][68];
    __shared__ float ws[64][128];
    int tid = threadIdx.x;
    int R0  = blockIdx.x * 64;
    int ty  = tid >> 4;
    int tx  = tid & 15;

    {
        int sr = tid >> 2;
        int l4 = tid & 3;
        int grow = R0 + sr;
        bool ok = grow < N;
        const float* orow = out + (size_t)grow * FO;
        #pragma unroll
        for (int q = 0; q < 4; ++q) {
            int j0 = (l4 + 4 * q) * 4;
            float4 a = ok ? *(const float4*)&orow[j0] : make_float4(0.f, 0.f, 0.f, 0.f);
            xs[j0 + 0][sr] = a.x;
            xs[j0 + 1][sr] = a.y;
            xs[j0 + 2][sr] = a.z;
            xs[j0 + 3][sr] = a.w;
        }
    }
    #pragma unroll
    for (int q = 0; q < 8; ++q) {
        int f = tid + q * 256;
        *(float4*)&ws[f >> 5][(f & 31) * 4] = *(const float4*)&W2[(size_t)f * 4];
    }
    __syncthreads();

    float acc[4][8];
    #pragma unroll
    for (int i = 0; i < 4; ++i)
        #pragma unroll
        for (int j = 0; j < 8; ++j) acc[i][j] = 0.f;

    #pragma unroll 4
    for (int k = 0; k < FH; ++k) {
        float4 a  = *(const float4*)&xs[k][ty * 4];
        float4 bl = *(const float4*)&ws[k][tx * 4];
        float4 bh = *(const float4*)&ws[k][64 + tx * 4];
        float av[4] = {a.x, a.y, a.z, a.w};
        float bv[8] = {bl.x, bl.y, bl.z, bl.w, bh.x, bh.y, bh.z, bh.w};
        #pragma unroll
        for (int i = 0; i < 4; ++i)
            #pragma unroll
            for (int j = 0; j < 8; ++j)
                acc[i][j] = fmaf(av[i], bv[j], acc[i][j]);
    }

    float4 b2l = *(const float4*)&b2[tx * 4];
    float4 b2h = *(const float4*)&b2[64 + tx * 4];
    #pragma unroll
    for (int i = 0; i < 4; ++i) {
        int row = R0 + ty * 4 + i;
        if (row < N) {
            float* o = out + (size_t)row * FO;
            *(float4*)&o[tx * 4] = make_float4(acc[i][0] + b2l.x, acc[i][1] + b2l.y,
                                               acc[i][2] + b2l.z, acc[i][3] + b2l.w);
            *(float4*)&o[64 + tx * 4] = make_float4(acc[i][4] + b2h.x, acc[i][5] + b2h.y,
                                                    acc[i][6] + b2h.z, acc[i][7] + b2h.w);
        }
    }
}

// ---------------- fallback (atomic scatter) pieces — all fp32 ----------------

__global__ void expand_hs1_kernel(float* __restrict__ out, int N) {
    int row = blockIdx.x * 4 + (threadIdx.x >> 6);
    if (row >= N) return;
    int lane = threadIdx.x & 63;
    float v = bf2f(((const ushort*)out)[(size_t)row * 256 + 128 + lane]);
    out[(size_t)row * FO + FH + lane] = v;
}

__global__ void zero_half_kernel(float* __restrict__ out, int half, int N) {
    int i = blockIdx.x * 256 + threadIdx.x;
    if (i >= N * FH) return;
    out[(size_t)(i >> 6) * FO + half + (i & 63)] = 0.f;
}

__global__ void scatter_half_kernel(const int* __restrict__ src, const int* __restrict__ dst,
                                    const float* __restrict__ dinv, float* __restrict__ out,
                                    int rh, int wh, int E) {
    int e = blockIdx.x * 4 + (threadIdx.x >> 6);
    if (e >= E) return;
    int lane = threadIdx.x & 63;
    int s = src[e];
    int d = dst[e];
    float w = dinv[s] * dinv[d];
    atomicAdd(&out[(size_t)d * FO + wh + lane], out[(size_t)s * FO + rh + lane] * w);
}

// lower = relu(lower_agg + dv^2*upper_own + b1)
__global__ void finish1_kernel(float* __restrict__ out, const float* __restrict__ dinv,
                               const float* __restrict__ b1, int N) {
    int i = blockIdx.x * 256 + threadIdx.x;
    if (i >= N * FH) return;
    int row = i >> 6;
    int c   = i & 63;
    size_t base = (size_t)row * FO;
    float dv = dinv[row];
    out[base + c] = fmaxf(out[base + c] + dv * dv * out[base + FH + c] + b1[c], 0.f);
}

// lower = upper_agg + dv^2*lower_own   (combined for mm2)
__global__ void finish2_kernel(float* __restrict__ out, const float* __restrict__ dinv, int N) {
    int i = blockIdx.x * 256 + threadIdx.x;
    if (i >= N * FH) return;
    int row = i >> 6;
    int c   = i & 63;
    size_t base = (size_t)row * FO;
    float dv = dinv[row];
    out[base + c] = out[base + FH + c] + dv * dv * out[base + c];
}

extern "C" void kernel_launch(void* const* d_in, const int* in_sizes, int n_in,
                              void* d_out, int out_size, void* d_ws, size_t ws_size,
                              hipStream_t stream) {
    const float* x  = (const float*)d_in[0];
    const int*   ei = (const int*)d_in[1];
    const float* W1 = (const float*)d_in[2];
    const float* b1 = (const float*)d_in[3];
    const float* W2 = (const float*)d_in[4];
    const float* b2 = (const float*)d_in[5];
    float* out = (float*)d_out;

    int N = in_sizes[0] / FI;     // 50000
    int E = in_sizes[1] / 2;      // 1600000
    const int* src = ei;
    const int* dst = ei + E;

    char* w = (char*)d_ws;
    float* dinv      = (float*)w;            w += (size_t)N * 4;
    int*   cnt       = (int*)w;              w += (size_t)N * 4;
    int*   row_start = (int*)w;              w += (size_t)N * 4;
    int*   pos       = (int*)w;              w += (size_t)N * 4;
    int*   blksum    = (int*)w;              w += 256 * 4;
    int2*  rec       = (int2*)w;             w += (size_t)E * 8;   // 8B aligned
    size_t need = (size_t)(w - (char*)d_ws);  // ~13.6 MB (proven available in r5)

    int nb = (N + 1023) / 1024;

    zero_i32<<<(N + 255) / 256, 256, 0, stream>>>(cnt, N);
    deg_cnt_kernel<<<(E + 1023) / 1024, 256, 0, stream>>>(dst, cnt, E);
    dinv_kernel<<<(N + 255) / 256, 256, 0, stream>>>(cnt, dinv, N);

    if (ws_size >= need) {
        scan_block_kernel<<<nb, 256, 0, stream>>>(cnt, row_start, blksum, N);
        scan_top_kernel<<<1, 64, 0, stream>>>(blksum, nb);
        scan_add_kernel<<<(N + 255) / 256, 256, 0, stream>>>(row_start, pos, blksum, N);
        edge_sort_kernel<<<(E + 255) / 256, 256, 0, stream>>>(src, dst, dinv, pos, rec, E);

        mm1_tiled<<<(N + 127) / 128, 256, 0, stream>>>(x, W1, out, N);
        gather_relu_kernel<<<(N + 3) / 4, 256, 0, stream>>>(rec, row_start, cnt, dinv, b1, out, N);
        gather_comb_kernel<<<(N + 3) / 4, 256, 0, stream>>>(rec, row_start, cnt, dinv, out, N);
        mm2_tiled<<<(N + 63) / 64, 256, 0, stream>>>(W2, b2, out, N);
    } else {
        // fallback: atomic scatter path, all fp32
        mm1_tiled<<<(N + 127) / 128, 256, 0, stream>>>(x, W1, out, N);
        expand_hs1_kernel<<<(N + 3) / 4, 256, 0, stream>>>(out, N);
        zero_half_kernel<<<((N * FH) + 255) / 256, 256, 0, stream>>>(out, 0, N);
        scatter_half_kernel<<<(E + 3) / 4, 256, 0, stream>>>(src, dst, dinv, out, FH, 0, E);
        finish1_kernel<<<((N * FH) + 255) / 256, 256, 0, stream>>>(out, dinv, b1, N);
        zero_half_kernel<<<((N * FH) + 255) / 256, 256, 0, stream>>>(out, FH, N);
        scatter_half_kernel<<<(E + 3) / 4, 256, 0, stream>>>(src, dst, dinv, out, 0, FH, E);
        finish2_kernel<<<((N * FH) + 255) / 256, 256, 0, stream>>>(out, dinv, N);
        mm2_tiled<<<(N + 63) / 64, 256, 0, stream>>>(W2, b2, out, N);
    }
}